// Round 5
// baseline (201.272 us; speedup 1.0000x reference)
//
#include <hip/hip_runtime.h>

// AAF loss, round 5: single-dispatch, algebraically-lean stage 2.
// LDS per halo pixel-class: a = clip(p), (D, L) = (ln a - ln b, ln b), b = clip(1-p);
// U[i] = sum_c fma(a, D, L)  (self "entropy" with b ~ 1-a).
// Per neighbor: sum_c kl = U[np] - sum_c a_n[c]*D_h[c] - sum_c L_h[c];
// inner loop is 1 ds_read_b32 + 1 fmac per class. Edge classes = {lab, nlab}
// (interior case), corrected exactly via dynamic LDS reads of (a, D, L) - no logf.
// Fallback branchless 19-class path for nlab > 18 (border pad / ignore labels).
// Finalization fused: device-scope atomics into Fin + last-block-done reduction.

#define NC 19
#define HH 512
#define WW 512
#define NB 2
#define TS 16
#define HS 18                          // TS + 2 halo
#define HP (HS * HS)                   // 324
#define NBLK (NB * (HH / TS) * (WW / TS))   // 2048
#define LOGEPS -9.210340371976182f     // log(1e-4)

struct Fin {
    double e_sum, ne_sum;
    unsigned long long ec, nc;
    unsigned int done;
};

__global__ __launch_bounds__(256, 2) void k_fused(const float* __restrict__ preds,
                                                  const int* __restrict__ targets,
                                                  const float* __restrict__ w_edge,
                                                  const float* __restrict__ w_not_edge,
                                                  Fin* __restrict__ fin,
                                                  float* __restrict__ out) {
    __shared__ float  A[HP * NC];    // a, pixel-major stride 19 (coprime 32 -> conflict-free b32)
    __shared__ float2 DL[HP * NC];   // (D, L)
    __shared__ float  U[HP];         // sum_c fma(a, D, L)
    __shared__ int    TG[HP];        // labels incl. halo (255 for image-OOB)
    __shared__ float  swe[NC], swn[NC];

    const int tid = threadIdx.x;
    const int bx = blockIdx.x, by = blockIdx.y, n = blockIdx.z;

    // per-block class-weight softmax
    if (tid < NC) {
        {
            float a = w_edge[tid * 3 + 0], b = w_edge[tid * 3 + 1], c = w_edge[tid * 3 + 2];
            float m = fmaxf(a, fmaxf(b, c));
            float ea = __expf(a - m), eb = __expf(b - m), ec = __expf(c - m);
            swe[tid] = ea / (ea + eb + ec);
        }
        {
            float a = w_not_edge[tid * 3 + 0], b = w_not_edge[tid * 3 + 1], c = w_not_edge[tid * 3 + 2];
            float m = fmaxf(a, fmaxf(b, c));
            float ea = __expf(a - m), eb = __expf(b - m), ec = __expf(c - m);
            swn[tid] = ea / (ea + eb + ec);
        }
    }

    const int* tg = targets + (n << 18);
    const float* pbase = preds + (size_t)n * NC * 4096;

    // ---- stage 1: halo softmax -> (a, D, L, U) into LDS ----
    for (int i = tid; i < HP; i += 256) {
        const int hy = i / HS, hx = i - hy * HS;
        const int y = by * TS + hy - 1;
        const int x = bx * TS + hx - 1;
        float* Ar = &A[i * NC];
        float2* Dr = &DL[i * NC];
        if (((unsigned)y >= (unsigned)HH) | ((unsigned)x >= (unsigned)WW)) {
            TG[i] = 255;
#pragma unroll
            for (int c = 0; c < NC; ++c) {
                Ar[c] = 1e-4f;
                Dr[c] = make_float2(LOGEPS, 0.0f);   // la = LOGEPS, lb = 0
            }
            U[i] = (float)NC * (1e-4f * LOGEPS);
        } else {
            TG[i] = tg[(y << 9) + x];
            const float fy = (float)(y * 63) / 511.0f;
            const float fx = (float)(x * 63) / 511.0f;
            const int y0 = (int)fy, x0 = (int)fx;
            const float wy = fy - (float)y0, wx = fx - (float)x0;
            const int y1 = min(y0 + 1, 63), x1 = min(x0 + 1, 63);
            const float omwy = 1.0f - wy, omwx = 1.0f - wx;

            float v[NC];
            float m = -1e30f;
#pragma unroll
            for (int c = 0; c < NC; ++c) {
                const float* pc_ = pbase + c * 4096;
                const float p00 = pc_[(y0 << 6) + x0];
                const float p10 = pc_[(y1 << 6) + x0];
                const float p01 = pc_[(y0 << 6) + x1];
                const float p11 = pc_[(y1 << 6) + x1];
                const float a = p00 * omwy + p10 * wy;
                const float b = p01 * omwy + p11 * wy;
                const float vv = a * omwx + b * wx;
                v[c] = vv;
                m = fmaxf(m, vv);
            }
            float s = 0.0f;
#pragma unroll
            for (int c = 0; c < NC; ++c) { v[c] = __expf(v[c] - m); s += v[c]; }
            const float inv = 1.0f / s;
            float u = 0.0f;
#pragma unroll
            for (int c = 0; c < NC; ++c) {
                const float p = v[c] * inv;
                const float a = fmaxf(p, 1e-4f);
                const float la = __logf(a);
                const float lb = __logf(fmaxf(1.0f - p, 1e-4f));
                const float Dc = la - lb;
                Ar[c] = a;
                Dr[c] = make_float2(Dc, lb);
                u = fmaf(a, Dc, u + lb);     // u += a*D + L
            }
            U[i] = u;
        }
    }
    __syncthreads();

    // ---- stage 2: per-pixel loss ----
    const int ty = tid >> 4, tx = tid & 15;
    const int hi = (ty + 1) * HS + (tx + 1);
    const int lab = TG[hi];

    float e_s = 0.0f, ne_s = 0.0f;
    int e_c = 0, ne_c = 0;

    if (lab <= NC - 1) {
        float D[NC], L[NC];
        float Lsum = 0.0f;
        const float2* DLh = &DL[hi * NC];
#pragma unroll
        for (int c = 0; c < NC; ++c) {
            const float2 dl = DLh[c];
            D[c] = dl.x; L[c] = dl.y;
            Lsum += dl.y;
        }
        const float2 dhL = DLh[lab];             // dynamic index (LDS, not regs)
        const float DhL = dhL.x, LhL = dhL.y;

        const int DOFF[8] = {-HS - 1, -HS, -HS + 1, -1, 1, HS - 1, HS, HS + 1};
#pragma unroll
        for (int k = 0; k < 8; ++k) {
            const int off = DOFF[k];
            const int rlab = TG[hi - off];       // reversed-offset ignore source
            const int np = hi + off;
            const int nlab = TG[np];
            const float* An = &A[np * NC];

            float accx = 0.0f;
#pragma unroll
            for (int c = 0; c < NC; ++c) accx = fmaf(An[c], D[c], accx);
            const float klsum = U[np] - accx - Lsum;

            float ek, sub; int pc;
            if (nlab <= NC - 1) {                // interior fast path
                const float2* DLn = &DL[np * NC];
                const float a1 = An[lab];
                const float2 d1 = DLn[lab];
                const float kl1 = fmaf(a1, d1.x - DhL, d1.y - LhL);
                const float a2 = An[nlab];
                const float2 d2 = DLn[nlab];
                const float2 h2 = DLh[nlab];
                const float kl2 = fmaf(a2, d2.x - h2.x, d2.y - h2.y);
                const bool df = (lab != nlab);
                const float w = df ? 1.0f : 0.0f;
                ek = w * (fmaxf(3.0f - kl1, 0.0f) + fmaxf(3.0f - kl2, 0.0f));
                sub = w * (kl1 + kl2);
                pc = df ? 2 : 0;
            } else {                             // pad/ignore neighbor fallback
                const unsigned mask = (nlab == 255) ? 0x7FFFFu : (1u << lab);
                const float2* DLn = &DL[np * NC];
                ek = 0.0f; sub = 0.0f;
#pragma unroll
                for (int c = 0; c < NC; ++c) {
                    const float2 dn = DLn[c];
                    const float kl = fmaf(An[c], dn.x - D[c], dn.y - L[c]);
                    const float ef = (float)((mask >> c) & 1u);
                    ek = fmaf(ef, fmaxf(3.0f - kl, 0.0f), ek);
                    sub = fmaf(ef, kl, sub);
                }
                pc = __popc(mask);
            }
            const bool valid = (rlab <= NC - 1);
            const float vf = valid ? 1.0f : 0.0f;
            e_s = fmaf(vf, ek, e_s);
            ne_s = fmaf(vf, klsum - sub, ne_s);
            e_c += valid ? pc : 0;
            ne_c += valid ? (NC - pc) : 0;
        }
        e_s *= swe[lab];
        ne_s *= swn[lab];
    }

    // ---- block reduction ----
#pragma unroll
    for (int off = 32; off > 0; off >>= 1) {
        e_s  += __shfl_down(e_s, off, 64);
        ne_s += __shfl_down(ne_s, off, 64);
        e_c  += __shfl_down(e_c, off, 64);
        ne_c += __shfl_down(ne_c, off, 64);
    }
    __shared__ float r_es[4], r_ns[4];
    __shared__ int r_ec[4], r_nc[4];
    const int wid = tid >> 6, lane = tid & 63;
    if (lane == 0) { r_es[wid] = e_s; r_ns[wid] = ne_s; r_ec[wid] = e_c; r_nc[wid] = ne_c; }
    __syncthreads();
    if (tid == 0) {
        float tes = 0.0f, tns = 0.0f;
        int tec = 0, tnc = 0;
#pragma unroll
        for (int w = 0; w < 4; ++w) { tes += r_es[w]; tns += r_ns[w]; tec += r_ec[w]; tnc += r_nc[w]; }
        atomicAdd(&fin->e_sum, (double)tes);
        atomicAdd(&fin->ne_sum, (double)tns);
        atomicAdd(&fin->ec, (unsigned long long)tec);
        atomicAdd(&fin->nc, (unsigned long long)tnc);
        __threadfence();
        const unsigned prev = atomicAdd(&fin->done, 1u);
        if (prev == (unsigned)(NBLK - 1)) {      // last block finalizes
            __threadfence();
            const double es = atomicAdd(&fin->e_sum, 0.0);
            const double ns = atomicAdd(&fin->ne_sum, 0.0);
            const double ec = (double)atomicAdd(&fin->ec, 0ull);
            const double nc = (double)atomicAdd(&fin->nc, 0ull);
            const double ecd = ec < 1.0 ? 1.0 : ec;
            const double ncd = nc < 1.0 ? 1.0 : nc;
            out[0] = (float)((es / ecd) * 0.01 + (ns / ncd) * 0.01);
        }
    }
}

extern "C" void kernel_launch(void* const* d_in, const int* in_sizes, int n_in,
                              void* d_out, int out_size, void* d_ws, size_t ws_size,
                              hipStream_t stream) {
    const float* preds      = (const float*)d_in[0];  // (2,19,64,64) fp32
    const int*   targets    = (const int*)d_in[1];    // (2,512,512) int32
    const float* w_edge     = (const float*)d_in[2];  // (1,1,1,19,1,3) fp32
    const float* w_not_edge = (const float*)d_in[3];

    Fin* fin = (Fin*)d_ws;
    hipMemsetAsync(fin, 0, sizeof(Fin), stream);      // captured as a memset node

    dim3 grid(WW / TS, HH / TS, NB);
    k_fused<<<grid, 256, 0, stream>>>(preds, targets, w_edge, w_not_edge, fin, (float*)d_out);
}

// Round 6
// 115.334 us; speedup vs baseline: 1.7451x; 1.7451x over previous
//
#include <hip/hip_runtime.h>

// AAF loss, round 6: R4 structure (2 dispatches, 3 blocks/CU, branchless) +
// R5 algebra (U + dot + 2-class corrections), fp16 LDS, v_dot2_f32_f16.
// Per halo pixel-class: a = clip(p), D = ln a - ln b, L = ln b (b = clip(1-p)),
// packed as class-pair half2, row stride 11 words (conflict-free). U = sum_c(aD+L) fp32.
// Interior blocks (no OOB halo, labels 0..18): per neighbor
//   sum_c kl = U_n - dot2(a_n, D_h) - Lsum_h;  edge classes = {lab, nlab} corrected
// exactly via dynamic LDS reads (no logf). Border blocks: general masked path.

#define NC 19
#define HH 512
#define WW 512
#define NB 2
#define TS 16
#define HS 18                          // TS + 2 halo
#define HP (HS * HS)                   // 324
#define NPAIR 10                       // ceil(19/2) class pairs
#define RS 11                          // padded row stride (words) -> conflict-free
#define NBLK (NB * (HH / TS) * (WW / TS))   // 2048
#define LOGEPS -9.210340371976182f     // log(1e-4)

typedef _Float16 f16x2 __attribute__((ext_vector_type(2)));

#if __has_builtin(__builtin_amdgcn_fdot2)
#define FDOT2(a, b, c) __builtin_amdgcn_fdot2((a), (b), (c), false)
#else
#define FDOT2(a, b, c) fmaf((float)(a)[1], (float)(b)[1], fmaf((float)(a)[0], (float)(b)[0], (c)))
#endif

struct Part { float es, ns; int ec, nc; };

__device__ __forceinline__ float extf(f16x2 v, int h) {
    return h ? (float)v[1] : (float)v[0];
}

__global__ __launch_bounds__(256, 3) void k_fused(const float* __restrict__ preds,
                                                  const int* __restrict__ targets,
                                                  const float* __restrict__ w_edge,
                                                  const float* __restrict__ w_not_edge,
                                                  Part* __restrict__ pb) {
    __shared__ f16x2 A2[HP * RS];   // a  (class pairs)
    __shared__ f16x2 D2[HP * RS];   // D = la - lb
    __shared__ f16x2 L2[HP * RS];   // L = lb
    __shared__ float U[HP];         // sum_c (a*D + L), fp32
    __shared__ int   TG[HP];        // labels incl. halo (255 for image-OOB)
    __shared__ float swe[NC], swn[NC];

    const int tid = threadIdx.x;
    const int bx = blockIdx.x, by = blockIdx.y, n = blockIdx.z;

    if (tid < NC) {
        {
            float a = w_edge[tid * 3 + 0], b = w_edge[tid * 3 + 1], c = w_edge[tid * 3 + 2];
            float m = fmaxf(a, fmaxf(b, c));
            float ea = __expf(a - m), eb = __expf(b - m), ec = __expf(c - m);
            swe[tid] = ea / (ea + eb + ec);
        }
        {
            float a = w_not_edge[tid * 3 + 0], b = w_not_edge[tid * 3 + 1], c = w_not_edge[tid * 3 + 2];
            float m = fmaxf(a, fmaxf(b, c));
            float ea = __expf(a - m), eb = __expf(b - m), ec = __expf(c - m);
            swn[tid] = ea / (ea + eb + ec);
        }
    }

    const int* tg = targets + (n << 18);
    const float* pbase = preds + (size_t)n * NC * 4096;

    // ---- stage 1: halo softmax -> packed (a, D, L) + U into LDS ----
    for (int i = tid; i < HP; i += 256) {
        const int hy = i / HS, hx = i - hy * HS;
        const int y = by * TS + hy - 1;
        const int x = bx * TS + hx - 1;
        float aarr[NPAIR * 2], Darr[NPAIR * 2], Larr[NPAIR * 2];
        float u;
        if (((unsigned)y >= (unsigned)HH) | ((unsigned)x >= (unsigned)WW)) {
            TG[i] = 255;
#pragma unroll
            for (int c = 0; c < NC; ++c) { aarr[c] = 1e-4f; Darr[c] = LOGEPS; Larr[c] = 0.0f; }
            u = (float)NC * (1e-4f * LOGEPS);
        } else {
            TG[i] = tg[(y << 9) + x];
            const float fy = (float)(y * 63) / 511.0f;
            const float fx = (float)(x * 63) / 511.0f;
            const int y0 = (int)fy, x0 = (int)fx;
            const float wy = fy - (float)y0, wx = fx - (float)x0;
            const int y1 = min(y0 + 1, 63), x1 = min(x0 + 1, 63);
            const float omwy = 1.0f - wy, omwx = 1.0f - wx;

            float v[NC];
            float m = -1e30f;
#pragma unroll
            for (int c = 0; c < NC; ++c) {
                const float* pc_ = pbase + c * 4096;
                const float p00 = pc_[(y0 << 6) + x0];
                const float p10 = pc_[(y1 << 6) + x0];
                const float p01 = pc_[(y0 << 6) + x1];
                const float p11 = pc_[(y1 << 6) + x1];
                const float a = p00 * omwy + p10 * wy;
                const float b = p01 * omwy + p11 * wy;
                const float vv = a * omwx + b * wx;
                v[c] = vv;
                m = fmaxf(m, vv);
            }
            float s = 0.0f;
#pragma unroll
            for (int c = 0; c < NC; ++c) { v[c] = __expf(v[c] - m); s += v[c]; }
            const float inv = 1.0f / s;
            u = 0.0f;
#pragma unroll
            for (int c = 0; c < NC; ++c) {
                const float p = v[c] * inv;
                const float a = fmaxf(p, 1e-4f);
                const float la = __logf(a);
                const float lb = __logf(fmaxf(1.0f - p, 1e-4f));
                aarr[c] = a; Darr[c] = la - lb; Larr[c] = lb;
                u = fmaf(a, Darr[c], u + lb);
            }
        }
        aarr[19] = 0.0f; Darr[19] = 0.0f; Larr[19] = 0.0f;   // pad class
        U[i] = u;
#pragma unroll
        for (int j = 0; j < NPAIR; ++j) {
            A2[i * RS + j] = (f16x2){(_Float16)aarr[2 * j], (_Float16)aarr[2 * j + 1]};
            D2[i * RS + j] = (f16x2){(_Float16)Darr[2 * j], (_Float16)Darr[2 * j + 1]};
            L2[i * RS + j] = (f16x2){(_Float16)Larr[2 * j], (_Float16)Larr[2 * j + 1]};
        }
    }
    __syncthreads();

    // ---- stage 2 ----
    const int ty = tid >> 4, tx = tid & 15;
    const int hi = (ty + 1) * HS + (tx + 1);
    const int lab = TG[hi];
    const bool interior_blk = (bx > 0) & (bx < 31) & (by > 0) & (by < 31);

    float e_s = 0.0f, ne_s = 0.0f;
    int e_c = 0, ne_c = 0;
    const int DOFF[8] = {-HS - 1, -HS, -HS + 1, -1, 1, HS - 1, HS, HS + 1};

    if (interior_blk) {
        // -------- fast path: no OOB, no ignore labels anywhere in halo --------
        f16x2 Dh2[NPAIR];
        float Lsum = 0.0f;
        const f16x2 one2 = {(_Float16)1.0f, (_Float16)1.0f};
#pragma unroll
        for (int j = 0; j < NPAIR; ++j) {
            Dh2[j] = D2[hi * RS + j];
            Lsum = FDOT2(L2[hi * RS + j], one2, Lsum);
        }
        const int plab = lab >> 1, hlab = lab & 1;
        const float DhL = extf(D2[hi * RS + plab], hlab);
        const float LhL = extf(L2[hi * RS + plab], hlab);

#pragma unroll
        for (int k = 0; k < 8; ++k) {
            const int np = hi + DOFF[k];
            const int nlab = TG[np];
            const int nb_ = np * RS;
            float dot = 0.0f;
#pragma unroll
            for (int j = 0; j < NPAIR; ++j) dot = FDOT2(A2[nb_ + j], Dh2[j], dot);
            const float klsum = U[np] - dot - Lsum;

            // kl at c = lab
            const float a1 = extf(A2[nb_ + plab], hlab);
            const float kl1 = fmaf(a1, extf(D2[nb_ + plab], hlab) - DhL,
                                   extf(L2[nb_ + plab], hlab) - LhL);
            // kl at c = nlab
            const int pn = nlab >> 1, hn = nlab & 1;
            const float a2 = extf(A2[nb_ + pn], hn);
            const float kl2 = fmaf(a2, extf(D2[nb_ + pn], hn) - extf(D2[hi * RS + pn], hn),
                                   extf(L2[nb_ + pn], hn) - extf(L2[hi * RS + pn], hn));

            const bool df = (lab != nlab);
            const float w = df ? 1.0f : 0.0f;
            e_s = fmaf(w, fmaxf(3.0f - kl1, 0.0f) + fmaxf(3.0f - kl2, 0.0f), e_s);
            ne_s += klsum - w * (kl1 + kl2);
            e_c += df ? 2 : 0;
        }
        ne_c = 8 * NC - e_c;
        e_s *= swe[lab];
        ne_s *= swn[lab];
    } else if (lab <= NC - 1) {
        // -------- border path: general masked, branchless per class --------
        f16x2 Dh2[NPAIR], Lh2[NPAIR];
#pragma unroll
        for (int j = 0; j < NPAIR; ++j) { Dh2[j] = D2[hi * RS + j]; Lh2[j] = L2[hi * RS + j]; }
        const unsigned mlab = 1u << lab;
#pragma unroll
        for (int k = 0; k < 8; ++k) {
            const int off = DOFF[k];
            const int rlab = TG[hi - off];
            const int np = hi + off;
            const int nlab = TG[np];
            const unsigned mask = (nlab <= NC - 1) ? (mlab ^ (1u << nlab))
                                : ((nlab == 255) ? 0x7FFFFu : mlab);
            const int nb_ = np * RS;
            float ek = 0.0f, nk = 0.0f;
#pragma unroll
            for (int j = 0; j < NPAIR; ++j) {
                const f16x2 an = A2[nb_ + j];
                const f16x2 dn = D2[nb_ + j];
                const f16x2 ln_ = L2[nb_ + j];
#pragma unroll
                for (int h = 0; h < 2; ++h) {
                    const int c = 2 * j + h;
                    if (c >= NC) break;   // compile-time for unrolled loop
                    const float kl = fmaf((float)an[h], (float)dn[h] - (float)Dh2[j][h],
                                          (float)ln_[h] - (float)Lh2[j][h]);
                    const float ef = (float)((mask >> c) & 1u);
                    ek = fmaf(ef, fmaxf(3.0f - kl, 0.0f), ek);
                    nk = fmaf(1.0f - ef, kl, nk);
                }
            }
            const bool valid = (rlab <= NC - 1);
            const float vf = valid ? 1.0f : 0.0f;
            e_s = fmaf(vf, ek, e_s);
            ne_s = fmaf(vf, nk, ne_s);
            const int pc = __popc(mask);
            e_c += valid ? pc : 0;
            ne_c += valid ? (NC - pc) : 0;
        }
        e_s *= swe[lab];
        ne_s *= swn[lab];
    }

    // ---- block reduction ----
#pragma unroll
    for (int off = 32; off > 0; off >>= 1) {
        e_s  += __shfl_down(e_s, off, 64);
        ne_s += __shfl_down(ne_s, off, 64);
        e_c  += __shfl_down(e_c, off, 64);
        ne_c += __shfl_down(ne_c, off, 64);
    }
    __shared__ float r_es[4], r_ns[4];
    __shared__ int r_ec[4], r_nc[4];
    const int wid = tid >> 6, lane = tid & 63;
    if (lane == 0) { r_es[wid] = e_s; r_ns[wid] = ne_s; r_ec[wid] = e_c; r_nc[wid] = ne_c; }
    __syncthreads();
    if (tid == 0) {
        float tes = 0.0f, tns = 0.0f;
        int tec = 0, tnc = 0;
#pragma unroll
        for (int w = 0; w < 4; ++w) { tes += r_es[w]; tns += r_ns[w]; tec += r_ec[w]; tnc += r_nc[w]; }
        const int bid = (blockIdx.z * gridDim.y + blockIdx.y) * gridDim.x + blockIdx.x;
        pb[bid].es = tes; pb[bid].ns = tns; pb[bid].ec = tec; pb[bid].nc = tnc;
    }
}

// ---------------- final reduce (1 block) ----------------
__global__ __launch_bounds__(256) void k_final(const Part* __restrict__ pb,
                                               float* __restrict__ out) {
    const int tid = threadIdx.x;
    double es = 0.0, ns = 0.0;
    long long ec = 0, nc = 0;
    for (int i = tid; i < NBLK; i += 256) {
        es += (double)pb[i].es; ns += (double)pb[i].ns;
        ec += pb[i].ec; nc += pb[i].nc;
    }
#pragma unroll
    for (int off = 32; off > 0; off >>= 1) {
        es += __shfl_down(es, off, 64);
        ns += __shfl_down(ns, off, 64);
        ec += __shfl_down(ec, off, 64);
        nc += __shfl_down(nc, off, 64);
    }
    __shared__ double ses[4], sns[4];
    __shared__ long long sec[4], snc[4];
    const int wid = tid >> 6, lane = tid & 63;
    if (lane == 0) { ses[wid] = es; sns[wid] = ns; sec[wid] = ec; snc[wid] = nc; }
    __syncthreads();
    if (tid == 0) {
        double tes = 0.0, tns = 0.0;
        long long tec = 0, tnc = 0;
#pragma unroll
        for (int w = 0; w < 4; ++w) { tes += ses[w]; tns += sns[w]; tec += sec[w]; tnc += snc[w]; }
        double ecd = (double)tec; if (ecd < 1.0) ecd = 1.0;
        double ncd = (double)tnc; if (ncd < 1.0) ncd = 1.0;
        out[0] = (float)((tes / ecd) * 0.01 + (tns / ncd) * 0.01);
    }
}

extern "C" void kernel_launch(void* const* d_in, const int* in_sizes, int n_in,
                              void* d_out, int out_size, void* d_ws, size_t ws_size,
                              hipStream_t stream) {
    const float* preds      = (const float*)d_in[0];  // (2,19,64,64) fp32
    const int*   targets    = (const int*)d_in[1];    // (2,512,512) int32
    const float* w_edge     = (const float*)d_in[2];  // (1,1,1,19,1,3) fp32
    const float* w_not_edge = (const float*)d_in[3];

    Part* pb = (Part*)d_ws;   // 2048 * 16 B; every slot written by k_fused

    dim3 grid(WW / TS, HH / TS, NB);
    k_fused<<<grid, 256, 0, stream>>>(preds, targets, w_edge, w_not_edge, pb);
    k_final<<<1, 256, 0, stream>>>(pb, (float*)d_out);
}